// Round 9
// baseline (244.180 us; speedup 1.0000x reference)
//
#include <hip/hip_runtime.h>
#include <hip/hip_bf16.h>

// PatchAttentionLayer R15 (= R14 + direct-MFMA gram, transposed Pg).
//   gram: NO staging LDS, NO K-loop barriers. MFMA fragments loaded directly
//         from L2 (2x float4 -> cvt_pk -> short8 in regs). Rowsums recovered
//         from A-fragment loads via __shfl_xor q-group combine (waves 0/2).
//         Pg stored TRANSPOSED [col][row] -> vectorized float4 acc stores.
//         Still zeroes Ghat + Acc. grid (16 ks, 8 b, 3 tt).
//   reduce_mirror: reads transposed Pg; stages 32x32 subtile in LDS [32][33]
//         for row-major Gbf/Ghat writes; mirror written straight from regs.
//   stats_quad / zmida / bcF2 / tvg / out_mfma: identical to R14.
// 7 dispatches.

#define BB 8
#define CC 256
#define NPIX 4096
#define PTOT 32768
#define EPSV 1e-5f
#define SCALEV 0.125f

// ---- workspace layout (float offsets) ----
#define OFF_PG    0L          // 384*16384 = 6291456 (TRANSPOSED tiles [col][row])
#define OFF_SP    6291456L    // 32768
#define OFF_S     6324224L    // 2048
#define OFF_GHAT  6326272L    // 65536
#define OFF_XBAR  6391808L    // 256
#define OFF_WP    6392064L    // 196608
#define OFF_WKTF  6588672L    // 65536
#define OFF_WVTF  6654208L    // 65536
#define OFF_CVEC  6719744L    // 768
#define OFF_ACC   6720512L    // 12288
#define OFF_GBF   6732800L    // 262144 (8*65536 ushort)
#define OFF_WQT   6994944L    // 32768
#define OFF_WKT   7027712L    // 32768
#define OFF_WVB   7060480L    // 32768
#define OFF_ZT    7093248L    // 32768
#define OFF_FT    7126016L    // 262144 (ushort)
#define OFF_TBF   7388160L    // 262144 (ushort)
// total 7650304 floats = 30.6 MB

// accumulator offsets inside OFF_ACC (floats); zeroed by gram spare blocks
#define ACC_U    0      // 8*256
#define ACC_W    2048   // 8*256
#define ACC_Y    4096   // 256
#define ACC_R    4352   // 256
#define ACC_H    4608   // 8*256
#define ACC_G    6656   // 8*256
#define ACC_VG   8704   // 8*256
#define ACC_SCAL 10752  // [0]=dkq, [1+b]=dwq[b]
#define ACC_TOT  12288

typedef __attribute__((ext_vector_type(8))) short short8;
typedef __attribute__((ext_vector_type(4))) float f32x4;

#define MFMA16(a, b, c) __builtin_amdgcn_mfma_f32_16x16x32_bf16((a), (b), (c), 0, 0, 0)

__device__ __forceinline__ ushort f2bf(float f) {
    union { float f; unsigned u; } v; v.f = f;
    const unsigned r = (v.u + 0x7FFFu + ((v.u >> 16) & 1u)) >> 16;
    return (ushort)r;
}

__device__ __forceinline__ float bf2f(ushort u) {
    union { unsigned u; float f; } v; v.u = ((unsigned)u) << 16;
    return v.f;
}

__device__ __forceinline__ ushort2 f2bf2(float a, float b) {
    __hip_bfloat162 h = __float22bfloat162_rn(float2{a, b});
    union { __hip_bfloat162 h; ushort2 u; } v; v.h = h;
    return v.u;
}

// two float4 (8 consecutive fp32 along k) -> short8 bf16 fragment word
__device__ __forceinline__ short8 pack8(const float4 u0, const float4 u1) {
    union { short8 s; ushort2 u2[4]; } t;
    t.u2[0] = f2bf2(u0.x, u0.y);
    t.u2[1] = f2bf2(u0.z, u0.w);
    t.u2[2] = f2bf2(u1.x, u1.y);
    t.u2[3] = f2bf2(u1.z, u1.w);
    return t.s;
}

__device__ __forceinline__ float block_reduce(float v, float* red, int tid) {
    red[tid] = v; __syncthreads();
    for (int st = 128; st > 0; st >>= 1) {
        if (tid < st) red[tid] += red[tid + st];
        __syncthreads();
    }
    float r = red[0]; __syncthreads();
    return r;
}

__device__ __forceinline__ float2 wred2(float a, float b, float* red8, int tid) {
    #pragma unroll
    for (int s = 32; s > 0; s >>= 1) {
        a += __shfl_xor(a, s);
        b += __shfl_xor(b, s);
    }
    if ((tid & 63) == 0) { red8[(tid >> 6) * 2] = a; red8[(tid >> 6) * 2 + 1] = b; }
    __syncthreads();
    const float ra = red8[0] + red8[2] + red8[4] + red8[6];
    const float rb = red8[1] + red8[3] + red8[5] + red8[7];
    __syncthreads();
    return float2{ra, rb};
}

// ---- Gram, direct-MFMA (R15): no staging LDS, no K-loop barriers ----
// grid (16 ks, 8 b, 3 tt): tt=0 -> (0,0); tt=1 -> (1,1); tt=2 -> (0,1)
// Pg tile stored TRANSPOSED: Pt[col*128 + row].
__global__ __launch_bounds__(256, 2) void gram_mfma(const float* __restrict__ x,
                                                    float* __restrict__ Pg,
                                                    float* __restrict__ Sp,
                                                    float* __restrict__ Ghat,
                                                    float* __restrict__ Acc) {
    __shared__ float rs[128];
    const int tid = threadIdx.x;
    const int ks = blockIdx.x, b = blockIdx.y, tt = blockIdx.z;
    const int lb = (tt * 8 + b) * 16 + ks;
    if (lb < 64) {
        #pragma unroll
        for (int i = 0; i < 4; ++i) Ghat[lb * 1024 + i * 256 + tid] = 0.f;
    } else if (lb < 76) {
        const int base = (lb - 64) * 1024;
        #pragma unroll
        for (int i = 0; i < 4; ++i) Acc[base + i * 256 + tid] = 0.f;
    }
    const int it = (tt == 1) ? 1 : 0;
    const int jt = (tt == 0) ? 0 : 1;
    const bool diag = (tt < 2);
    const int i0 = it * 128, j0 = jt * 128, k0 = ks * 256;
    const float* xb = x + (long)b * CC * NPIX;
    const int wave = tid >> 6, lane = tid & 63;
    const int wr = (wave >> 1) * 64, wc = (wave & 1) * 64;
    const int m = lane & 15, q8 = (lane >> 4) * 8;

    const float* Arow = xb + (long)i0 * NPIX + k0;
    const float* Brow = xb + (long)(diag ? i0 : j0) * NPIX + k0;

    f32x4 acc[4][4];
    #pragma unroll
    for (int a = 0; a < 4; ++a)
        #pragma unroll
        for (int q = 0; q < 4; ++q) acc[a][q] = (f32x4){0.f, 0.f, 0.f, 0.f};
    float rsum[4] = {0.f, 0.f, 0.f, 0.f};

    #pragma unroll
    for (int kk = 0; kk < 8; ++kk) {
        const int kb = kk * 32 + q8;
        short8 af[4], bfv[4];
        #pragma unroll
        for (int a = 0; a < 4; ++a) {
            const long ro = (long)(wr + a * 16 + m) * NPIX + kb;
            const float4 u0 = *(const float4*)&Arow[ro];
            const float4 u1 = *(const float4*)&Arow[ro + 4];
            rsum[a] += u0.x + u0.y + u0.z + u0.w + u1.x + u1.y + u1.z + u1.w;
            af[a] = pack8(u0, u1);
        }
        #pragma unroll
        for (int q = 0; q < 4; ++q) {
            const long ro = (long)(wc + q * 16 + m) * NPIX + kb;
            const float4 u0 = *(const float4*)&Brow[ro];
            const float4 u1 = *(const float4*)&Brow[ro + 4];
            bfv[q] = pack8(u0, u1);
        }
        #pragma unroll
        for (int a = 0; a < 4; ++a)
            #pragma unroll
            for (int q = 0; q < 4; ++q)
                acc[a][q] = MFMA16(af[a], bfv[q], acc[a][q]);
    }

    if (diag) {
        // combine the 4 q-groups (lanes m, m+16, m+32, m+48) per row
        #pragma unroll
        for (int a = 0; a < 4; ++a) {
            rsum[a] += __shfl_xor(rsum[a], 16);
            rsum[a] += __shfl_xor(rsum[a], 32);
        }
        // rows 0-63 from wave 0, 64-127 from wave 2 (waves 1/3 duplicate af)
        if (((wave & 1) == 0) && ((lane >> 4) == 0)) {
            #pragma unroll
            for (int a = 0; a < 4; ++a) rs[wr + a * 16 + m] = rsum[a];
        }
        __syncthreads();
        if (tid < 128) Sp[(((long)ks * 8 + b) * 2 + it) * 128 + tid] = rs[tid];
    }

    float* Pt = Pg + (((long)ks * 8 + b) * 3 + tt) * 16384;
    const int rq = (lane >> 4) * 4;
    #pragma unroll
    for (int a = 0; a < 4; ++a) {
        #pragma unroll
        for (int q = 0; q < 4; ++q) {
            const int col = wc + q * 16 + m;
            *(f32x4*)&Pt[(long)col * 128 + wr + a * 16 + rq] = acc[a][q];
        }
    }
}

// ---- reduce partials (transposed Pg) -> Gbf (mirrored), Ghat (atomic); S; xbar ----
// grid 385. blk<384: (tt = blk>>7, sub = (blk>>3)&15, b = blk&7), 16-deep ks sum.
__global__ __launch_bounds__(256) void reduce_mirror(const float* __restrict__ Pg,
                                                     const float* __restrict__ Sp,
                                                     ushort* __restrict__ Gbf,
                                                     float* __restrict__ Ghat,
                                                     float* __restrict__ S,
                                                     float* __restrict__ xbar) {
    const int blk = blockIdx.x, tid = threadIdx.x;
    if (blk == 384) {
        const int it2 = tid >> 7, rr = tid & 127;
        float xacc = 0.f;
        for (int b = 0; b < BB; ++b) {
            float acc = 0.f;
            #pragma unroll
            for (int ks = 0; ks < 16; ++ks)
                acc += Sp[(((long)ks * 8 + b) * 2 + it2) * 128 + rr];
            S[b * 256 + tid] = acc;
            xacc += acc;
        }
        xbar[tid] = xacc * (1.0f / PTOT);
        return;
    }
    __shared__ float tile[32][33];
    const int tt = blk >> 7;
    const int sub = (blk >> 3) & 15;
    const int b = blk & 7;
    const int sr = (sub >> 2) * 32, sc = (sub & 3) * 32;
    const int it = (tt == 1) ? 1 : 0;
    const int jt = (tt == 0) ? 0 : 1;
    const bool offd = (tt == 2);
    const int gi0 = it * 128 + sr, gj0 = jt * 128 + sc;
    const int rr = tid >> 3, c4 = (tid & 7) * 4;
    const float inv = 1.0f / PTOT;

    // Pg transposed: float4 along row-dim -> s_i = G[gi0 + c4+i][gj0 + rr]
    float s0 = 0.f, s1 = 0.f, s2 = 0.f, s3 = 0.f;
    #pragma unroll
    for (int ks = 0; ks < 16; ++ks) {
        const float4 v = *(const float4*)&Pg[(((long)ks * 8 + b) * 3 + tt) * 16384
                                             + (long)(sc + rr) * 128 + sr + c4];
        s0 += v.x; s1 += v.y; s2 += v.z; s3 += v.w;
    }
    // stage: tile[R][C] = G[gi0+R][gj0+C]
    tile[c4 + 0][rr] = s0; tile[c4 + 1][rr] = s1;
    tile[c4 + 2][rr] = s2; tile[c4 + 3][rr] = s3;
    __syncthreads();
    const float t0 = tile[rr][c4 + 0], t1 = tile[rr][c4 + 1];
    const float t2 = tile[rr][c4 + 2], t3 = tile[rr][c4 + 3];
    ushort4 w;
    w.x = f2bf(t0); w.y = f2bf(t1); w.z = f2bf(t2); w.w = f2bf(t3);
    *(ushort4*)&Gbf[(long)b * 65536 + (long)(gi0 + rr) * 256 + gj0 + c4] = w;
    float* gd = &Ghat[(long)(gi0 + rr) * 256 + gj0 + c4];
    atomicAdd(gd + 0, t0 * inv);
    atomicAdd(gd + 1, t1 * inv);
    atomicAdd(gd + 2, t2 * inv);
    atomicAdd(gd + 3, t3 * inv);
    if (offd) {
        // mirror: Gbf[gj0+rr][gi0+c4+i] = G[gi0+c4+i][gj0+rr] = s_i (own regs)
        ushort4 tw;
        tw.x = f2bf(s0); tw.y = f2bf(s1); tw.z = f2bf(s2); tw.w = f2bf(s3);
        *(ushort4*)&Gbf[(long)b * 65536 + (long)(gj0 + rr) * 256 + gi0 + c4] = tw;
        float* gm = &Ghat[(long)(gj0 + rr) * 256 + gi0 + c4];
        atomicAdd(gm + 0, s0 * inv);
        atomicAdd(gm + 1, s1 * inv);
        atomicAdd(gm + 2, s2 * inv);
        atomicAdd(gm + 3, s3 * inv);
    }
}

// ---- BN stats; 4 output channels per block, grid (64,3) ----
__global__ __launch_bounds__(256) void stats_quad(const float* __restrict__ Wq, const float* __restrict__ Wk,
                           const float* __restrict__ Wv, const float* __restrict__ Ghat,
                           const float* __restrict__ xbar,
                           const float* bq, const float* gq, const float* betaq,
                           const float* bk, const float* gk, const float* betak,
                           const float* bv, const float* gv, const float* betav,
                           float* __restrict__ Wp, float* __restrict__ cvec,
                           ushort* __restrict__ WqT, ushort* __restrict__ WkT,
                           ushort* __restrict__ Wvb, float* __restrict__ WkTf,
                           float* __restrict__ WvTf) {
    const int og = blockIdx.x, t = blockIdx.y, tid = threadIdx.x;
    const int o0 = og * 4;
    const float* Wt  = t == 0 ? Wq : (t == 1 ? Wk : Wv);
    const float* bt  = t == 0 ? bq : (t == 1 ? bk : bv);
    const float* gt  = t == 0 ? gq : (t == 1 ? gk : gv);
    const float* bet = t == 0 ? betaq : (t == 1 ? betak : betav);
    __shared__ float wrows[4][256];
    __shared__ float red8[8];
    #pragma unroll
    for (int i = 0; i < 4; ++i) wrows[i][tid] = Wt[(o0 + i) * 256 + tid];
    const float xb = xbar[tid];
    __syncthreads();
    const float* grow = Ghat + (long)tid * 256;
    float tj[4] = {0.f, 0.f, 0.f, 0.f};
    #pragma unroll 8
    for (int k = 0; k < 256; k += 4) {
        const float4 g = *(const float4*)&grow[k];
        #pragma unroll
        for (int i = 0; i < 4; ++i)
            tj[i] += g.x * wrows[i][k]     + g.y * wrows[i][k + 1]
                   + g.z * wrows[i][k + 2] + g.w * wrows[i][k + 3];
    }
    #pragma unroll
    for (int i = 0; i < 4; ++i) {
        const int o = o0 + i;
        const float wv = wrows[i][tid];
        const float2 qw = wred2(wv * tj[i], wv * xb, red8, tid);
        const float bo = bt[o];
        const float mu = qw.y + bo;
        const float var = qw.x + 2.f * bo * mu - bo * bo - mu * mu;
        const float a = gt[o] * rsqrtf(var + EPSV);
        const float wpv = a * wv;
        Wp[(long)t * 65536 + o * 256 + tid] = wpv;
        const ushort wb = f2bf(wpv);
        if (t == 0) {
            WqT[(long)tid * 256 + o] = wb;
        } else if (t == 1) {
            WkT[(long)tid * 256 + o] = wb;
            WkTf[(long)tid * 256 + o] = wpv;
        } else {
            Wvb[(long)o * 256 + tid] = wb;
            WvTf[(long)tid * 256 + o] = wpv;
        }
        if (tid == 0) cvec[t * 256 + o] = a * (bo - mu) + bet[o];
    }
}

// ---- 128x128 MFMA tile, K=256, fragments direct from L2; D[col][row] bf16 ----
__device__ __forceinline__ void gemm_tile0(const ushort* __restrict__ Ab,
                                           const ushort* __restrict__ Bb,
                                           ushort* __restrict__ Db,
                                           int m0, int n0, int tid) {
    const int wave = tid >> 6, lane = tid & 63;
    const int wr = (wave >> 1) * 64, wc = (wave & 1) * 64;
    const int m = lane & 15, q8 = (lane >> 4) * 8;
    f32x4 acc[4][4];
    #pragma unroll
    for (int a = 0; a < 4; ++a)
        #pragma unroll
        for (int q = 0; q < 4; ++q) acc[a][q] = (f32x4){0.f, 0.f, 0.f, 0.f};
    #pragma unroll
    for (int kk = 0; kk < 8; ++kk) {
        short8 af[4], bfv[4];
        #pragma unroll
        for (int a = 0; a < 4; ++a)
            af[a] = *(const short8*)&Ab[(long)(m0 + wr + a * 16 + m) * 256 + kk * 32 + q8];
        #pragma unroll
        for (int q = 0; q < 4; ++q)
            bfv[q] = *(const short8*)&Bb[(long)(n0 + wc + q * 16 + m) * 256 + kk * 32 + q8];
        #pragma unroll
        for (int a = 0; a < 4; ++a)
            #pragma unroll
            for (int q = 0; q < 4; ++q)
                acc[a][q] = MFMA16(af[a], bfv[q], acc[a][q]);
    }
    const int rq = (lane >> 4) * 4;
    #pragma unroll
    for (int a = 0; a < 4; ++a) {
        #pragma unroll
        for (int q = 0; q < 4; ++q) {
            const int col = n0 + wc + q * 16 + m;
            #pragma unroll
            for (int reg = 0; reg < 4; ++reg)
                Db[(long)col * 256 + (m0 + wr + a * 16 + rq + reg)] = f2bf(acc[a][q][reg]);
        }
    }
}

// ---- zmida: {Z GEMM (0-3) | u,w 4-way (4-35) | y,r 4-way (36-39)} ----
__global__ __launch_bounds__(256) void zmida(const ushort* __restrict__ WkT,
                                             const ushort* __restrict__ WqT,
                                             ushort* __restrict__ ZT,
                                             const float* __restrict__ Wp,
                                             const float* __restrict__ WkTf,
                                             const float* __restrict__ WvTf,
                                             const float* __restrict__ S,
                                             const float* __restrict__ cvec,
                                             float* __restrict__ Acc) {
    const int blk = blockIdx.x, tid = threadIdx.x;
    __shared__ float sa[64], sb[64];
    if (blk < 4) {
        gemm_tile0(WkT, WqT, ZT, (blk >> 1) * 128, (blk & 1) * 128, tid);
        return;
    }
    if (blk < 36) {
        const int b = (blk - 4) >> 2, j0 = ((blk - 4) & 3) * 64;
        if (tid < 64) sa[tid] = S[b * 256 + j0 + tid];
        __syncthreads();
        float uu = 0.f, ww = 0.f;
        #pragma unroll 8
        for (int i = 0; i < 64; ++i) {
            const float sv = sa[i];
            uu += WvTf[(long)(j0 + i) * 256 + tid] * sv;
            ww += WkTf[(long)(j0 + i) * 256 + tid] * sv;
        }
        atomicAdd(&Acc[ACC_U + b * 256 + tid], uu);
        atomicAdd(&Acc[ACC_W + b * 256 + tid], ww);
    } else {
        const int o0 = (blk - 36) * 64;
        if (tid < 64) { sa[tid] = cvec[o0 + tid]; sb[tid] = cvec[256 + o0 + tid]; }
        __syncthreads();
        float yy = 0.f, rr = 0.f;
        #pragma unroll 8
        for (int i = 0; i < 64; ++i) {
            yy += Wp[65536L + (long)(o0 + i) * 256 + tid] * sa[i];
            rr += Wp[(long)(o0 + i) * 256 + tid] * sb[i];
        }
        atomicAdd(&Acc[ACC_Y + tid], yy);
        atomicAdd(&Acc[ACC_R + tid], rr);
    }
}

// ---- bcF2: {F GEMM (0-31) | h 4-way (32-63) | g 4-way (64-95) | scalars (96)} ----
__global__ __launch_bounds__(256) void bcF2(const ushort* __restrict__ Gbf,
                                            const ushort* __restrict__ ZT,
                                            ushort* __restrict__ FT,
                                            const float* __restrict__ Wp,
                                            const float* __restrict__ cvec,
                                            float* __restrict__ Acc) {
    const int blk = blockIdx.x, tid = threadIdx.x;
    __shared__ float sa[64];
    __shared__ float red[256];
    if (blk < 32) {
        const int bz = blk >> 2, t = blk & 3;
        gemm_tile0(Gbf + (long)bz * 65536, ZT, FT + (long)bz * 65536,
                   (t >> 1) * 128, (t & 1) * 128, tid);
        return;
    }
    if (blk < 64) {
        const int b = (blk - 32) >> 2, o0 = ((blk - 32) & 3) * 64;
        if (tid < 64) sa[tid] = Acc[ACC_W + b * 256 + o0 + tid];
        __syncthreads();
        float hh = 0.f;
        #pragma unroll 8
        for (int i = 0; i < 64; ++i)
            hh += Wp[(long)(o0 + i) * 256 + tid] * sa[i];
        atomicAdd(&Acc[ACC_H + b * 256 + tid], hh);
    } else if (blk < 96) {
        const int b = (blk - 64) >> 2, o0 = ((blk - 64) & 3) * 64;
        if (tid < 64) sa[tid] = Acc[ACC_Y + o0 + tid];
        __syncthreads();
        float gg = 0.f;
        #pragma unroll 8
        for (int i = 0; i < 64; ++i)
            gg += bf2f(Gbf[(long)b * 65536 + (long)(o0 + i) * 256 + tid]) * sa[i];
        atomicAdd(&Acc[ACC_G + b * 256 + tid], gg);
    } else {
        const float cq = cvec[tid], ck = cvec[256 + tid];
        const float dkq = block_reduce(cq * ck, red, tid);
        if (tid == 0) Acc[ACC_SCAL] = dkq;
        for (int b = 0; b < BB; ++b) {
            const float dwq = block_reduce(Acc[ACC_W + b * 256 + tid] * cq, red, tid);
            if (tid == 0) Acc[ACC_SCAL + 1 + b] = dwq;
        }
    }
}

// ---- tvg: {T GEMM + epilogue (0-31) | vg 4-way (32-63)} ----
__global__ __launch_bounds__(256) void tvg(const ushort* __restrict__ Wvb,
                                           const ushort* __restrict__ FT,
                                           ushort* __restrict__ Tbf,
                                           const float* __restrict__ WvTf,
                                           const float* __restrict__ cvec,
                                           float* __restrict__ Acc) {
    const int blk = blockIdx.x, tid = threadIdx.x;
    __shared__ float sa[64];
    if (blk < 32) {
        const int bz = blk >> 2, t = blk & 3;
        const int m0 = (t >> 1) * 128, n0 = (t & 1) * 128;
        const ushort* Fb = FT + (long)bz * 65536;
        const int wave = tid >> 6, lane = tid & 63;
        const int wr = (wave >> 1) * 64, wc = (wave & 1) * 64;
        const int m = lane & 15, q8 = (lane >> 4) * 8;
        f32x4 acc[4][4];
        #pragma unroll
        for (int a = 0; a < 4; ++a)
            #pragma unroll
            for (int q = 0; q < 4; ++q) acc[a][q] = (f32x4){0.f, 0.f, 0.f, 0.f};
        #pragma unroll
        for (int kk = 0; kk < 8; ++kk) {
            short8 af[4], bfv[4];
            #pragma unroll
            for (int a = 0; a < 4; ++a)
                af[a] = *(const short8*)&Wvb[(long)(m0 + wr + a * 16 + m) * 256 + kk * 32 + q8];
            #pragma unroll
            for (int q = 0; q < 4; ++q)
                bfv[q] = *(const short8*)&Fb[(long)(n0 + wc + q * 16 + m) * 256 + kk * 32 + q8];
            #pragma unroll
            for (int a = 0; a < 4; ++a)
                #pragma unroll
                for (int q = 0; q < 4; ++q)
                    acc[a][q] = MFMA16(af[a], bfv[q], acc[a][q]);
        }
        const int rq = (lane >> 4) * 4;
        #pragma unroll
        for (int a = 0; a < 4; ++a) {
            #pragma unroll
            for (int q = 0; q < 4; ++q) {
                const int col = n0 + wc + q * 16 + m;
                const float rv = Acc[ACC_R + col];
                const float t2 = Acc[ACC_H + bz * 256 + col] + 4096.0f * rv;
                #pragma unroll
                for (int reg = 0; reg < 4; ++reg) {
                    const int row = m0 + wr + a * 16 + rq + reg;
                    const float val = SCALEV * (acc[a][q][reg]
                                                + Acc[ACC_U + bz * 256 + row] * rv
                                                + cvec[512 + row] * t2);
                    Tbf[(long)bz * 65536 + (long)row * 256 + col] = f2bf(val);
                }
            }
        }
    } else {
        const int b = (blk - 32) >> 2, j0 = ((blk - 32) & 3) * 64;
        if (tid < 64) sa[tid] = Acc[ACC_G + b * 256 + j0 + tid];
        __syncthreads();
        float vg = 0.f;
        #pragma unroll 8
        for (int i = 0; i < 64; ++i)
            vg += WvTf[(long)(j0 + i) * 256 + tid] * sa[i];
        atomicAdd(&Acc[ACC_VG + b * 256 + tid], vg);
    }
}

// ---- out = T x + off (off computed inline); grid (64, 8) ----
__global__ __launch_bounds__(256) void out_mfma(const ushort* __restrict__ Tbf,
                                                const float* __restrict__ x,
                                                const float* __restrict__ Acc,
                                                const float* __restrict__ cvec,
                                                float* __restrict__ out) {
    __shared__ __align__(16) ushort Bs[64 * 264];
    const int tid = threadIdx.x;
    const int p0 = blockIdx.x * 64;
    const int b = blockIdx.y;
    const float* xb = x + (long)b * CC * NPIX;
    const ushort* Tb = Tbf + (long)b * 65536;
    const float dkq = Acc[ACC_SCAL];
    const float dwqb = Acc[ACC_SCAL + 1 + b];

    const int c = tid & 15, kq = tid >> 4;
    #pragma unroll
    for (int kt = 0; kt < 4; ++kt) {
        const int k4 = kt * 64 + kq * 4;
        const int p = c * 4;
        const float4 v0 = *(const float4*)&xb[(long)(k4 + 0) * NPIX + p0 + p];
        const float4 v1 = *(const float4*)&xb[(long)(k4 + 1) * NPIX + p0 + p];
        const float4 v2 = *(const float4*)&xb[(long)(k4 + 2) * NPIX + p0 + p];
        const float4 v3 = *(const float4*)&xb[(long)(k4 + 3) * NPIX + p0 + p];
        ushort2 a01, a23;
        ushort4 w;
        a01 = f2bf2(v0.x, v1.x); a23 = f2bf2(v2.x, v3.x);
        w.x = a01.x; w.y = a01.y; w.z = a23.x; w.w = a23.y;
        *(ushort4*)&Bs[(p + 0) * 264 + k4] = w;
        a01 = f2bf2(v0.y, v1.y); a23 = f2bf2(v2.y, v3.y);
        w.x = a01.x; w.y = a01.y; w.z = a23.x; w.w = a23.y;
        *(ushort4*)&Bs[(p + 1) * 264 + k4] = w;
        a01 = f2bf2(v0.z, v1.z); a23 = f2bf2(v2.z, v3.z);
        w.x = a01.x; w.y = a01.y; w.z = a23.x; w.w = a23.y;
        *(ushort4*)&Bs[(p + 2) * 264 + k4] = w;
        a01 = f2bf2(v0.w, v1.w); a23 = f2bf2(v2.w, v3.w);
        w.x = a01.x; w.y = a01.y; w.z = a23.x; w.w = a23.y;
        *(ushort4*)&Bs[(p + 3) * 264 + k4] = w;
    }
    __syncthreads();

    const int wave = tid >> 6, lane = tid & 63;
    const int wr = wave * 64;
    const int m = lane & 15, q8 = (lane >> 4) * 8;
    f32x4 acc[4][4];
    #pragma unroll
    for (int a = 0; a < 4; ++a)
        #pragma unroll
        for (int q = 0; q < 4; ++q) acc[a][q] = (f32x4){0.f, 0.f, 0.f, 0.f};

    #pragma unroll
    for (int kk = 0; kk < 8; ++kk) {
        short8 af[4], bfv[4];
        #pragma unroll
        for (int a = 0; a < 4; ++a)
            af[a] = *(const short8*)&Tb[(long)(wr + a * 16 + m) * 256 + kk * 32 + q8];
        #pragma unroll
        for (int q = 0; q < 4; ++q)
            bfv[q] = *(const short8*)&Bs[(q * 16 + m) * 264 + kk * 32 + q8];
        #pragma unroll
        for (int a = 0; a < 4; ++a)
            #pragma unroll
            for (int q = 0; q < 4; ++q)
                acc[a][q] = MFMA16(af[a], bfv[q], acc[a][q]);
    }

    const int rq = (lane >> 4) * 4;
    #pragma unroll
    for (int a = 0; a < 4; ++a) {
        #pragma unroll
        for (int reg = 0; reg < 4; ++reg) {
            const int row = wr + a * 16 + rq + reg;
            const float off_ = SCALEV * (Acc[ACC_VG + b * 256 + row]
                                         + Acc[ACC_U + b * 256 + row] * dkq
                                         + cvec[512 + row] * (dwqb + 4096.0f * dkq));
            float* orow = &out[((long)b * CC + row) * NPIX + p0];
            #pragma unroll
            for (int q = 0; q < 4; ++q)
                orow[q * 16 + m] = acc[a][q][reg] + off_;
        }
    }
}

extern "C" void kernel_launch(void* const* d_in, const int* in_sizes, int n_in,
                              void* d_out, int out_size, void* d_ws, size_t ws_size,
                              hipStream_t stream) {
    const float* x     = (const float*)d_in[0];
    const float* Wq    = (const float*)d_in[1];
    const float* bq    = (const float*)d_in[2];
    const float* gq    = (const float*)d_in[3];
    const float* betaq = (const float*)d_in[4];
    const float* Wk    = (const float*)d_in[5];
    const float* bk    = (const float*)d_in[6];
    const float* gk    = (const float*)d_in[7];
    const float* betak = (const float*)d_in[8];
    const float* Wv    = (const float*)d_in[9];
    const float* bv    = (const float*)d_in[10];
    const float* gv    = (const float*)d_in[11];
    const float* betav = (const float*)d_in[12];
    float* ws = (float*)d_ws;

    float*  Pg   = ws + OFF_PG;
    float*  Sp   = ws + OFF_SP;
    float*  S    = ws + OFF_S;
    float*  Ghat = ws + OFF_GHAT;
    float*  Xbar = ws + OFF_XBAR;
    float*  Wp   = ws + OFF_WP;
    float*  WkTf = ws + OFF_WKTF;
    float*  WvTf = ws + OFF_WVTF;
    float*  cvec = ws + OFF_CVEC;
    float*  Acc  = ws + OFF_ACC;
    ushort* Gbf  = (ushort*)(ws + OFF_GBF);
    ushort* WqT  = (ushort*)(ws + OFF_WQT);
    ushort* WkT  = (ushort*)(ws + OFF_WKT);
    ushort* Wvb  = (ushort*)(ws + OFF_WVB);
    ushort* ZT   = (ushort*)(ws + OFF_ZT);
    ushort* FT   = (ushort*)(ws + OFF_FT);
    ushort* Tbf  = (ushort*)(ws + OFF_TBF);

    gram_mfma<<<dim3(16, 8, 3), 256, 0, stream>>>(x, Pg, Sp, Ghat, Acc);
    reduce_mirror<<<385, 256, 0, stream>>>(Pg, Sp, Gbf, Ghat, S, Xbar);
    stats_quad<<<dim3(64, 3), 256, 0, stream>>>(Wq, Wk, Wv, Ghat, Xbar,
                                                bq, gq, betaq, bk, gk, betak,
                                                bv, gv, betav, Wp, cvec,
                                                WqT, WkT, Wvb, WkTf, WvTf);
    zmida<<<40, 256, 0, stream>>>(WkT, WqT, ZT, Wp, WkTf, WvTf, S, cvec, Acc);
    bcF2<<<97, 256, 0, stream>>>(Gbf, ZT, FT, Wp, cvec, Acc);
    tvg<<<64, 256, 0, stream>>>(Wvb, FT, Tbf, WvTf, cvec, Acc);
    out_mfma<<<dim3(64, 8), 256, 0, stream>>>(Tbf, x, Acc, cvec, (float*)d_out);
}

// Round 10
// 189.921 us; speedup vs baseline: 1.2857x; 1.2857x over previous
//
#include <hip/hip_runtime.h>
#include <hip/hip_bf16.h>

// PatchAttentionLayer R16 = R14 revert (session best: 190.2 us).
// R15's direct-L2 gram regressed (uncoalesced 16B/lane fragment loads,
// gram 74-102us vs <=42 staged). Staged gram restored.
//   gram: ks=16 (384 blocks) -> Pg partials; zeroes Ghat + Acc; rowsums.
//   reduce_mirror: 385 blocks -> Gbf (mirrored), Ghat(atomic), S, xbar.
//   stats_quad: grid (64,3) -> Wp, transposes, cvec.
//   zmida: {Z GEMM (4) | u,w 4-way (32, atomic) | y,r 4-way (4, atomic)}.
//   bcF2:  {F GEMM (32) | h 4-way (32) | g 4-way (32) | scalars (1)}.
//   tvg:   {T GEMM + rank-1 epilogue (32) | vg 4-way (32, atomic)}.
//   out_mfma: out = T x + off; off computed inline from VGacc/Uacc/scalars.
// 7 dispatches; every chain stage (<=64-deep) overlaps >=32 GEMM blocks.

#define BB 8
#define CC 256
#define NPIX 4096
#define PTOT 32768
#define EPSV 1e-5f
#define SCALEV 0.125f

// ---- workspace layout (float offsets) ----
#define OFF_PG    0L          // 384*16384 = 6291456
#define OFF_SP    6291456L    // 32768
#define OFF_S     6324224L    // 2048
#define OFF_GHAT  6326272L    // 65536
#define OFF_XBAR  6391808L    // 256
#define OFF_WP    6392064L    // 196608
#define OFF_WKTF  6588672L    // 65536
#define OFF_WVTF  6654208L    // 65536
#define OFF_CVEC  6719744L    // 768
#define OFF_ACC   6720512L    // 12288
#define OFF_GBF   6732800L    // 262144 (8*65536 ushort)
#define OFF_WQT   6994944L    // 32768
#define OFF_WKT   7027712L    // 32768
#define OFF_WVB   7060480L    // 32768
#define OFF_ZT    7093248L    // 32768
#define OFF_FT    7126016L    // 262144 (ushort)
#define OFF_TBF   7388160L    // 262144 (ushort)
// total 7650304 floats = 30.6 MB

// accumulator offsets inside OFF_ACC (floats); zeroed by gram spare blocks
#define ACC_U    0      // 8*256
#define ACC_W    2048   // 8*256
#define ACC_Y    4096   // 256
#define ACC_R    4352   // 256
#define ACC_H    4608   // 8*256
#define ACC_G    6656   // 8*256
#define ACC_VG   8704   // 8*256
#define ACC_SCAL 10752  // [0]=dkq, [1+b]=dwq[b]
#define ACC_TOT  12288  // zeroed region (12 blocks x 1024)

typedef __attribute__((ext_vector_type(8))) short short8;
typedef __attribute__((ext_vector_type(4))) float f32x4;

#define MFMA16(a, b, c) __builtin_amdgcn_mfma_f32_16x16x32_bf16((a), (b), (c), 0, 0, 0)

__device__ __forceinline__ ushort f2bf(float f) {
    union { float f; unsigned u; } v; v.f = f;
    const unsigned r = (v.u + 0x7FFFu + ((v.u >> 16) & 1u)) >> 16;
    return (ushort)r;
}

__device__ __forceinline__ float bf2f(ushort u) {
    union { unsigned u; float f; } v; v.u = ((unsigned)u) << 16;
    return v.f;
}

__device__ __forceinline__ ushort2 f2bf2(float a, float b) {
    __hip_bfloat162 h = __float22bfloat162_rn(float2{a, b});
    union { __hip_bfloat162 h; ushort2 u; } v; v.h = h;
    return v.u;
}

__device__ __forceinline__ float block_reduce(float v, float* red, int tid) {
    red[tid] = v; __syncthreads();
    for (int st = 128; st > 0; st >>= 1) {
        if (tid < st) red[tid] += red[tid + st];
        __syncthreads();
    }
    float r = red[0]; __syncthreads();
    return r;
}

__device__ __forceinline__ float2 wred2(float a, float b, float* red8, int tid) {
    #pragma unroll
    for (int s = 32; s > 0; s >>= 1) {
        a += __shfl_xor(a, s);
        b += __shfl_xor(b, s);
    }
    if ((tid & 63) == 0) { red8[(tid >> 6) * 2] = a; red8[(tid >> 6) * 2 + 1] = b; }
    __syncthreads();
    const float ra = red8[0] + red8[2] + red8[4] + red8[6];
    const float rb = red8[1] + red8[3] + red8[5] + red8[7];
    __syncthreads();
    return float2{ra, rb};
}

// ---- Gram via MFMA: 128x128 upper tiles, ks=16; zeroes Ghat + Acc ----
__global__ __launch_bounds__(256, 2) void gram_mfma(const float* __restrict__ x,
                                                    float* __restrict__ Pg,
                                                    float* __restrict__ Sp,
                                                    float* __restrict__ Ghat,
                                                    float* __restrict__ Acc) {
    __shared__ __align__(16) ushort Ab[128 * 72];
    __shared__ __align__(16) ushort Bb[128 * 72];
    __shared__ float rs[128];
    const int tid = threadIdx.x;
    const int ks = blockIdx.x, b = blockIdx.y, tt = blockIdx.z;
    const int lb = (tt * 8 + b) * 16 + ks;
    if (lb < 64) {
        #pragma unroll
        for (int i = 0; i < 4; ++i) Ghat[lb * 1024 + i * 256 + tid] = 0.f;
    } else if (lb < 76) {
        const int base = (lb - 64) * 1024;
        #pragma unroll
        for (int i = 0; i < 4; ++i) Acc[base + i * 256 + tid] = 0.f;
    }
    const int it = (tt == 1) ? 1 : 0;
    const int jt = (tt == 0) ? 0 : 1;
    const bool diag = (tt < 2);
    const int i0 = it * 128, j0 = jt * 128, k0 = ks * 256;
    const float* xb = x + (long)b * CC * NPIX;
    const int c = tid & 15, rp = tid >> 4;
    const int wave = tid >> 6, lane = tid & 63;
    const int wr = (wave >> 1) * 64, wc = (wave & 1) * 64;
    const int m = lane & 15, q8 = (lane >> 4) * 8;

    if (tid < 128) rs[tid] = 0.f;
    float rloc[8] = {};
    f32x4 acc[4][4];
    #pragma unroll
    for (int a = 0; a < 4; ++a)
        #pragma unroll
        for (int q = 0; q < 4; ++q) acc[a][q] = (f32x4){0.f, 0.f, 0.f, 0.f};

    const float* Abase = xb + (long)i0 * NPIX + k0 + c * 4;
    const float* Bbase = xb + (long)j0 * NPIX + k0 + c * 4;

    float4 va[8], vb[8];
    #pragma unroll
    for (int pp = 0; pp < 8; ++pp)
        va[pp] = *(const float4*)&Abase[(long)(pp * 16 + rp) * NPIX];
    if (!diag) {
        #pragma unroll
        for (int pp = 0; pp < 8; ++pp)
            vb[pp] = *(const float4*)&Bbase[(long)(pp * 16 + rp) * NPIX];
    }

    for (int kc = 0; kc < 256; kc += 64) {
        __syncthreads();
        #pragma unroll
        for (int pp = 0; pp < 8; ++pp) {
            const int row = pp * 16 + rp;
            const float4 v = va[pp];
            rloc[pp] += v.x + v.y + v.z + v.w;
            const ushort2 w01 = f2bf2(v.x, v.y);
            const ushort2 w23 = f2bf2(v.z, v.w);
            ushort4 w; w.x = w01.x; w.y = w01.y; w.z = w23.x; w.w = w23.y;
            *(ushort4*)&Ab[row * 72 + c * 4] = w;
        }
        if (!diag) {
            #pragma unroll
            for (int pp = 0; pp < 8; ++pp) {
                const int row = pp * 16 + rp;
                const float4 v = vb[pp];
                const ushort2 w01 = f2bf2(v.x, v.y);
                const ushort2 w23 = f2bf2(v.z, v.w);
                ushort4 w; w.x = w01.x; w.y = w01.y; w.z = w23.x; w.w = w23.y;
                *(ushort4*)&Bb[row * 72 + c * 4] = w;
            }
        }
        const int kn = kc + 64;
        if (kn < 256) {
            #pragma unroll
            for (int pp = 0; pp < 8; ++pp)
                va[pp] = *(const float4*)&Abase[(long)(pp * 16 + rp) * NPIX + kn];
            if (!diag) {
                #pragma unroll
                for (int pp = 0; pp < 8; ++pp)
                    vb[pp] = *(const float4*)&Bbase[(long)(pp * 16 + rp) * NPIX + kn];
            }
        }
        __syncthreads();
        const ushort* Bsrc = diag ? Ab : Bb;
        #pragma unroll
        for (int kk = 0; kk < 2; ++kk) {
            short8 af[4], bfv[4];
            #pragma unroll
            for (int a = 0; a < 4; ++a)
                af[a] = *(const short8*)&Ab[(wr + a * 16 + m) * 72 + kk * 32 + q8];
            #pragma unroll
            for (int q = 0; q < 4; ++q)
                bfv[q] = *(const short8*)&Bsrc[(wc + q * 16 + m) * 72 + kk * 32 + q8];
            #pragma unroll
            for (int a = 0; a < 4; ++a)
                #pragma unroll
                for (int q = 0; q < 4; ++q)
                    acc[a][q] = MFMA16(af[a], bfv[q], acc[a][q]);
        }
    }
    if (diag) {
        #pragma unroll
        for (int pp = 0; pp < 8; ++pp) atomicAdd(&rs[pp * 16 + rp], rloc[pp]);
        __syncthreads();
        if (tid < 128) Sp[(((long)ks * 8 + b) * 2 + it) * 128 + tid] = rs[tid];
    }
    float* Pt = Pg + (((long)ks * 8 + b) * 3 + tt) * 16384;
    const int rq = (lane >> 4) * 4;
    #pragma unroll
    for (int a = 0; a < 4; ++a) {
        #pragma unroll
        for (int q = 0; q < 4; ++q) {
            const int col = wc + q * 16 + m;
            #pragma unroll
            for (int reg = 0; reg < 4; ++reg)
                Pt[(long)(wr + a * 16 + rq + reg) * 128 + col] = acc[a][q][reg];
        }
    }
}

// ---- reduce partials -> Gbf (mirrored), Ghat (atomic); S; xbar. grid 385 ----
__global__ __launch_bounds__(256) void reduce_mirror(const float* __restrict__ Pg,
                                                     const float* __restrict__ Sp,
                                                     ushort* __restrict__ Gbf,
                                                     float* __restrict__ Ghat,
                                                     float* __restrict__ S,
                                                     float* __restrict__ xbar) {
    const int blk = blockIdx.x, tid = threadIdx.x;
    if (blk == 384) {
        const int it2 = tid >> 7, rr = tid & 127;
        float xacc = 0.f;
        for (int b = 0; b < BB; ++b) {
            float acc = 0.f;
            #pragma unroll
            for (int ks = 0; ks < 16; ++ks)
                acc += Sp[(((long)ks * 8 + b) * 2 + it2) * 128 + rr];
            S[b * 256 + tid] = acc;
            xacc += acc;
        }
        xbar[tid] = xacc * (1.0f / PTOT);
        return;
    }
    __shared__ float tile[32][33];
    const int tt = blk >> 7;
    const int sub = (blk >> 3) & 15;
    const int b = blk & 7;
    const int sr = (sub >> 2) * 32, sc = (sub & 3) * 32;
    const int it = (tt == 1) ? 1 : 0;
    const int jt = (tt == 0) ? 0 : 1;
    const bool offd = (tt == 2);
    const int gi0 = it * 128 + sr, gj0 = jt * 128 + sc;
    const int r = tid >> 3, c4 = (tid & 7) * 4;
    const float inv = 1.0f / PTOT;

    float s0 = 0.f, s1 = 0.f, s2 = 0.f, s3 = 0.f;
    #pragma unroll
    for (int ks = 0; ks < 16; ++ks) {
        const float4 v = *(const float4*)&Pg[(((long)ks * 8 + b) * 3 + tt) * 16384
                                             + (long)(sr + r) * 128 + sc + c4];
        s0 += v.x; s1 += v.y; s2 += v.z; s3 += v.w;
    }
    ushort4 w;
    w.x = f2bf(s0); w.y = f2bf(s1); w.z = f2bf(s2); w.w = f2bf(s3);
    *(ushort4*)&Gbf[(long)b * 65536 + (long)(gi0 + r) * 256 + gj0 + c4] = w;
    float* gd = &Ghat[(long)(gi0 + r) * 256 + gj0 + c4];
    atomicAdd(gd + 0, s0 * inv);
    atomicAdd(gd + 1, s1 * inv);
    atomicAdd(gd + 2, s2 * inv);
    atomicAdd(gd + 3, s3 * inv);
    if (offd) {
        tile[r][c4 + 0] = s0; tile[r][c4 + 1] = s1;
        tile[r][c4 + 2] = s2; tile[r][c4 + 3] = s3;
        __syncthreads();
        const float t0 = tile[c4 + 0][r], t1 = tile[c4 + 1][r];
        const float t2 = tile[c4 + 2][r], t3 = tile[c4 + 3][r];
        ushort4 tw;
        tw.x = f2bf(t0); tw.y = f2bf(t1); tw.z = f2bf(t2); tw.w = f2bf(t3);
        *(ushort4*)&Gbf[(long)b * 65536 + (long)(gj0 + r) * 256 + gi0 + c4] = tw;
        float* gm = &Ghat[(long)(gj0 + r) * 256 + gi0 + c4];
        atomicAdd(gm + 0, t0 * inv);
        atomicAdd(gm + 1, t1 * inv);
        atomicAdd(gm + 2, t2 * inv);
        atomicAdd(gm + 3, t3 * inv);
    }
}

// ---- BN stats; 4 output channels per block, grid (64,3) ----
__global__ __launch_bounds__(256) void stats_quad(const float* __restrict__ Wq, const float* __restrict__ Wk,
                           const float* __restrict__ Wv, const float* __restrict__ Ghat,
                           const float* __restrict__ xbar,
                           const float* bq, const float* gq, const float* betaq,
                           const float* bk, const float* gk, const float* betak,
                           const float* bv, const float* gv, const float* betav,
                           float* __restrict__ Wp, float* __restrict__ cvec,
                           ushort* __restrict__ WqT, ushort* __restrict__ WkT,
                           ushort* __restrict__ Wvb, float* __restrict__ WkTf,
                           float* __restrict__ WvTf) {
    const int og = blockIdx.x, t = blockIdx.y, tid = threadIdx.x;
    const int o0 = og * 4;
    const float* Wt  = t == 0 ? Wq : (t == 1 ? Wk : Wv);
    const float* bt  = t == 0 ? bq : (t == 1 ? bk : bv);
    const float* gt  = t == 0 ? gq : (t == 1 ? gk : gv);
    const float* bet = t == 0 ? betaq : (t == 1 ? betak : betav);
    __shared__ float wrows[4][256];
    __shared__ float red8[8];
    #pragma unroll
    for (int i = 0; i < 4; ++i) wrows[i][tid] = Wt[(o0 + i) * 256 + tid];
    const float xb = xbar[tid];
    __syncthreads();
    const float* grow = Ghat + (long)tid * 256;
    float tj[4] = {0.f, 0.f, 0.f, 0.f};
    #pragma unroll 8
    for (int k = 0; k < 256; k += 4) {
        const float4 g = *(const float4*)&grow[k];
        #pragma unroll
        for (int i = 0; i < 4; ++i)
            tj[i] += g.x * wrows[i][k]     + g.y * wrows[i][k + 1]
                   + g.z * wrows[i][k + 2] + g.w * wrows[i][k + 3];
    }
    #pragma unroll
    for (int i = 0; i < 4; ++i) {
        const int o = o0 + i;
        const float wv = wrows[i][tid];
        const float2 qw = wred2(wv * tj[i], wv * xb, red8, tid);
        const float bo = bt[o];
        const float mu = qw.y + bo;
        const float var = qw.x + 2.f * bo * mu - bo * bo - mu * mu;
        const float a = gt[o] * rsqrtf(var + EPSV);
        const float wpv = a * wv;
        Wp[(long)t * 65536 + o * 256 + tid] = wpv;
        const ushort wb = f2bf(wpv);
        if (t == 0) {
            WqT[(long)tid * 256 + o] = wb;
        } else if (t == 1) {
            WkT[(long)tid * 256 + o] = wb;
            WkTf[(long)tid * 256 + o] = wpv;
        } else {
            Wvb[(long)o * 256 + tid] = wb;
            WvTf[(long)tid * 256 + o] = wpv;
        }
        if (tid == 0) cvec[t * 256 + o] = a * (bo - mu) + bet[o];
    }
}

// ---- 128x128 MFMA tile, K=256, fragments direct from L2; D[col][row] bf16 ----
__device__ __forceinline__ void gemm_tile0(const ushort* __restrict__ Ab,
                                           const ushort* __restrict__ Bb,
                                           ushort* __restrict__ Db,
                                           int m0, int n0, int tid) {
    const int wave = tid >> 6, lane = tid & 63;
    const int wr = (wave >> 1) * 64, wc = (wave & 1) * 64;
    const int m = lane & 15, q8 = (lane >> 4) * 8;
    f32x4 acc[4][4];
    #pragma unroll
    for (int a = 0; a < 4; ++a)
        #pragma unroll
        for (int q = 0; q < 4; ++q) acc[a][q] = (f32x4){0.f, 0.f, 0.f, 0.f};
    #pragma unroll
    for (int kk = 0; kk < 8; ++kk) {
        short8 af[4], bfv[4];
        #pragma unroll
        for (int a = 0; a < 4; ++a)
            af[a] = *(const short8*)&Ab[(long)(m0 + wr + a * 16 + m) * 256 + kk * 32 + q8];
        #pragma unroll
        for (int q = 0; q < 4; ++q)
            bfv[q] = *(const short8*)&Bb[(long)(n0 + wc + q * 16 + m) * 256 + kk * 32 + q8];
        #pragma unroll
        for (int a = 0; a < 4; ++a)
            #pragma unroll
            for (int q = 0; q < 4; ++q)
                acc[a][q] = MFMA16(af[a], bfv[q], acc[a][q]);
    }
    const int rq = (lane >> 4) * 4;
    #pragma unroll
    for (int a = 0; a < 4; ++a) {
        #pragma unroll
        for (int q = 0; q < 4; ++q) {
            const int col = n0 + wc + q * 16 + m;
            #pragma unroll
            for (int reg = 0; reg < 4; ++reg)
                Db[(long)col * 256 + (m0 + wr + a * 16 + rq + reg)] = f2bf(acc[a][q][reg]);
        }
    }
}

// ---- zmida: {Z GEMM (0-3) | u,w 4-way (4-35) | y,r 4-way (36-39)} ----
__global__ __launch_bounds__(256) void zmida(const ushort* __restrict__ WkT,
                                             const ushort* __restrict__ WqT,
                                             ushort* __restrict__ ZT,
                                             const float* __restrict__ Wp,
                                             const float* __restrict__ WkTf,
                                             const float* __restrict__ WvTf,
                                             const float* __restrict__ S,
                                             const float* __restrict__ cvec,
                                             float* __restrict__ Acc) {
    const int blk = blockIdx.x, tid = threadIdx.x;
    __shared__ float sa[64], sb[64];
    if (blk < 4) {
        gemm_tile0(WkT, WqT, ZT, (blk >> 1) * 128, (blk & 1) * 128, tid);
        return;
    }
    if (blk < 36) {
        const int b = (blk - 4) >> 2, j0 = ((blk - 4) & 3) * 64;
        if (tid < 64) sa[tid] = S[b * 256 + j0 + tid];
        __syncthreads();
        float uu = 0.f, ww = 0.f;
        #pragma unroll 8
        for (int i = 0; i < 64; ++i) {
            const float sv = sa[i];
            uu += WvTf[(long)(j0 + i) * 256 + tid] * sv;
            ww += WkTf[(long)(j0 + i) * 256 + tid] * sv;
        }
        atomicAdd(&Acc[ACC_U + b * 256 + tid], uu);
        atomicAdd(&Acc[ACC_W + b * 256 + tid], ww);
    } else {
        const int o0 = (blk - 36) * 64;
        if (tid < 64) { sa[tid] = cvec[o0 + tid]; sb[tid] = cvec[256 + o0 + tid]; }
        __syncthreads();
        float yy = 0.f, rr = 0.f;
        #pragma unroll 8
        for (int i = 0; i < 64; ++i) {
            yy += Wp[65536L + (long)(o0 + i) * 256 + tid] * sa[i];
            rr += Wp[(long)(o0 + i) * 256 + tid] * sb[i];
        }
        atomicAdd(&Acc[ACC_Y + tid], yy);
        atomicAdd(&Acc[ACC_R + tid], rr);
    }
}

// ---- bcF2: {F GEMM (0-31) | h 4-way (32-63) | g 4-way (64-95) | scalars (96)} ----
__global__ __launch_bounds__(256) void bcF2(const ushort* __restrict__ Gbf,
                                            const ushort* __restrict__ ZT,
                                            ushort* __restrict__ FT,
                                            const float* __restrict__ Wp,
                                            const float* __restrict__ cvec,
                                            float* __restrict__ Acc) {
    const int blk = blockIdx.x, tid = threadIdx.x;
    __shared__ float sa[64];
    __shared__ float red[256];
    if (blk < 32) {
        const int bz = blk >> 2, t = blk & 3;
        gemm_tile0(Gbf + (long)bz * 65536, ZT, FT + (long)bz * 65536,
                   (t >> 1) * 128, (t & 1) * 128, tid);
        return;
    }
    if (blk < 64) {
        const int b = (blk - 32) >> 2, o0 = ((blk - 32) & 3) * 64;
        if (tid < 64) sa[tid] = Acc[ACC_W + b * 256 + o0 + tid];
        __syncthreads();
        float hh = 0.f;
        #pragma unroll 8
        for (int i = 0; i < 64; ++i)
            hh += Wp[(long)(o0 + i) * 256 + tid] * sa[i];
        atomicAdd(&Acc[ACC_H + b * 256 + tid], hh);
    } else if (blk < 96) {
        const int b = (blk - 64) >> 2, o0 = ((blk - 64) & 3) * 64;
        if (tid < 64) sa[tid] = Acc[ACC_Y + o0 + tid];
        __syncthreads();
        float gg = 0.f;
        #pragma unroll 8
        for (int i = 0; i < 64; ++i)
            gg += bf2f(Gbf[(long)b * 65536 + (long)(o0 + i) * 256 + tid]) * sa[i];
        atomicAdd(&Acc[ACC_G + b * 256 + tid], gg);
    } else {
        const float cq = cvec[tid], ck = cvec[256 + tid];
        const float dkq = block_reduce(cq * ck, red, tid);
        if (tid == 0) Acc[ACC_SCAL] = dkq;
        for (int b = 0; b < BB; ++b) {
            const float dwq = block_reduce(Acc[ACC_W + b * 256 + tid] * cq, red, tid);
            if (tid == 0) Acc[ACC_SCAL + 1 + b] = dwq;
        }
    }
}

// ---- tvg: {T GEMM + epilogue (0-31) | vg 4-way (32-63)} ----
__global__ __launch_bounds__(256) void tvg(const ushort* __restrict__ Wvb,
                                           const ushort* __restrict__ FT,
                                           ushort* __restrict__ Tbf,
                                           const float* __restrict__ WvTf,
                                           const float* __restrict__ cvec,
                                           float* __restrict__ Acc) {
    const int blk = blockIdx.x, tid = threadIdx.x;
    __shared__ float sa[64];
    if (blk < 32) {
        const int bz = blk >> 2, t = blk & 3;
        const int m0 = (t >> 1) * 128, n0 = (t & 1) * 128;
        const ushort* Fb = FT + (long)bz * 65536;
        const int wave = tid >> 6, lane = tid & 63;
        const int wr = (wave >> 1) * 64, wc = (wave & 1) * 64;
        const int m = lane & 15, q8 = (lane >> 4) * 8;
        f32x4 acc[4][4];
        #pragma unroll
        for (int a = 0; a < 4; ++a)
            #pragma unroll
            for (int q = 0; q < 4; ++q) acc[a][q] = (f32x4){0.f, 0.f, 0.f, 0.f};
        #pragma unroll
        for (int kk = 0; kk < 8; ++kk) {
            short8 af[4], bfv[4];
            #pragma unroll
            for (int a = 0; a < 4; ++a)
                af[a] = *(const short8*)&Wvb[(long)(m0 + wr + a * 16 + m) * 256 + kk * 32 + q8];
            #pragma unroll
            for (int q = 0; q < 4; ++q)
                bfv[q] = *(const short8*)&Fb[(long)(n0 + wc + q * 16 + m) * 256 + kk * 32 + q8];
            #pragma unroll
            for (int a = 0; a < 4; ++a)
                #pragma unroll
                for (int q = 0; q < 4; ++q)
                    acc[a][q] = MFMA16(af[a], bfv[q], acc[a][q]);
        }
        const int rq = (lane >> 4) * 4;
        #pragma unroll
        for (int a = 0; a < 4; ++a) {
            #pragma unroll
            for (int q = 0; q < 4; ++q) {
                const int col = n0 + wc + q * 16 + m;
                const float rv = Acc[ACC_R + col];
                const float t2 = Acc[ACC_H + bz * 256 + col] + 4096.0f * rv;
                #pragma unroll
                for (int reg = 0; reg < 4; ++reg) {
                    const int row = m0 + wr + a * 16 + rq + reg;
                    const float val = SCALEV * (acc[a][q][reg]
                                                + Acc[ACC_U + bz * 256 + row] * rv
                                                + cvec[512 + row] * t2);
                    Tbf[(long)bz * 65536 + (long)row * 256 + col] = f2bf(val);
                }
            }
        }
    } else {
        const int b = (blk - 32) >> 2, j0 = ((blk - 32) & 3) * 64;
        if (tid < 64) sa[tid] = Acc[ACC_G + b * 256 + j0 + tid];
        __syncthreads();
        float vg = 0.f;
        #pragma unroll 8
        for (int i = 0; i < 64; ++i)
            vg += WvTf[(long)(j0 + i) * 256 + tid] * sa[i];
        atomicAdd(&Acc[ACC_VG + b * 256 + tid], vg);
    }
}

// ---- out = T x + off (off computed inline); grid (64, 8) ----
__global__ __launch_bounds__(256) void out_mfma(const ushort* __restrict__ Tbf,
                                                const float* __restrict__ x,
                                                const float* __restrict__ Acc,
                                                const float* __restrict__ cvec,
                                                float* __restrict__ out) {
    __shared__ __align__(16) ushort Bs[64 * 264];
    const int tid = threadIdx.x;
    const int p0 = blockIdx.x * 64;
    const int b = blockIdx.y;
    const float* xb = x + (long)b * CC * NPIX;
    const ushort* Tb = Tbf + (long)b * 65536;
    const float dkq = Acc[ACC_SCAL];
    const float dwqb = Acc[ACC_SCAL + 1 + b];

    const int c = tid & 15, kq = tid >> 4;
    #pragma unroll
    for (int kt = 0; kt < 4; ++kt) {
        const int k4 = kt * 64 + kq * 4;
        const int p = c * 4;
        const float4 v0 = *(const float4*)&xb[(long)(k4 + 0) * NPIX + p0 + p];
        const float4 v1 = *(const float4*)&xb[(long)(k4 + 1) * NPIX + p0 + p];
        const float4 v2 = *(const float4*)&xb[(long)(k4 + 2) * NPIX + p0 + p];
        const float4 v3 = *(const float4*)&xb[(long)(k4 + 3) * NPIX + p0 + p];
        ushort2 a01, a23;
        ushort4 w;
        a01 = f2bf2(v0.x, v1.x); a23 = f2bf2(v2.x, v3.x);
        w.x = a01.x; w.y = a01.y; w.z = a23.x; w.w = a23.y;
        *(ushort4*)&Bs[(p + 0) * 264 + k4] = w;
        a01 = f2bf2(v0.y, v1.y); a23 = f2bf2(v2.y, v3.y);
        w.x = a01.x; w.y = a01.y; w.z = a23.x; w.w = a23.y;
        *(ushort4*)&Bs[(p + 1) * 264 + k4] = w;
        a01 = f2bf2(v0.z, v1.z); a23 = f2bf2(v2.z, v3.z);
        w.x = a01.x; w.y = a01.y; w.z = a23.x; w.w = a23.y;
        *(ushort4*)&Bs[(p + 2) * 264 + k4] = w;
        a01 = f2bf2(v0.w, v1.w); a23 = f2bf2(v2.w, v3.w);
        w.x = a01.x; w.y = a01.y; w.z = a23.x; w.w = a23.y;
        *(ushort4*)&Bs[(p + 3) * 264 + k4] = w;
    }
    __syncthreads();

    const int wave = tid >> 6, lane = tid & 63;
    const int wr = wave * 64;
    const int m = lane & 15, q8 = (lane >> 4) * 8;
    f32x4 acc[4][4];
    #pragma unroll
    for (int a = 0; a < 4; ++a)
        #pragma unroll
        for (int q = 0; q < 4; ++q) acc[a][q] = (f32x4){0.f, 0.f, 0.f, 0.f};

    #pragma unroll
    for (int kk = 0; kk < 8; ++kk) {
        short8 af[4], bfv[4];
        #pragma unroll
        for (int a = 0; a < 4; ++a)
            af[a] = *(const short8*)&Tb[(long)(wr + a * 16 + m) * 256 + kk * 32 + q8];
        #pragma unroll
        for (int q = 0; q < 4; ++q)
            bfv[q] = *(const short8*)&Bs[(q * 16 + m) * 264 + kk * 32 + q8];
        #pragma unroll
        for (int a = 0; a < 4; ++a)
            #pragma unroll
            for (int q = 0; q < 4; ++q)
                acc[a][q] = MFMA16(af[a], bfv[q], acc[a][q]);
    }

    const int rq = (lane >> 4) * 4;
    #pragma unroll
    for (int a = 0; a < 4; ++a) {
        #pragma unroll
        for (int reg = 0; reg < 4; ++reg) {
            const int row = wr + a * 16 + rq + reg;
            const float off_ = SCALEV * (Acc[ACC_VG + b * 256 + row]
                                         + Acc[ACC_U + b * 256 + row] * dkq
                                         + cvec[512 + row] * (dwqb + 4096.0f * dkq));
            float* orow = &out[((long)b * CC + row) * NPIX + p0];
            #pragma unroll
            for (int q = 0; q < 4; ++q)
                orow[q * 16 + m] = acc[a][q][reg] + off_;
        }
    }
}

extern "C" void kernel_launch(void* const* d_in, const int* in_sizes, int n_in,
                              void* d_out, int out_size, void* d_ws, size_t ws_size,
                              hipStream_t stream) {
    const float* x     = (const float*)d_in[0];
    const float* Wq    = (const float*)d_in[1];
    const float* bq    = (const float*)d_in[2];
    const float* gq    = (const float*)d_in[3];
    const float* betaq = (const float*)d_in[4];
    const float* Wk    = (const float*)d_in[5];
    const float* bk    = (const float*)d_in[6];
    const float* gk    = (const float*)d_in[7];
    const float* betak = (const float*)d_in[8];
    const float* Wv    = (const float*)d_in[9];
    const float* bv    = (const float*)d_in[10];
    const float* gv    = (const float*)d_in[11];
    const float* betav = (const float*)d_in[12];
    float* ws = (float*)d_ws;

    float*  Pg   = ws + OFF_PG;
    float*  Sp   = ws + OFF_SP;
    float*  S    = ws + OFF_S;
    float*  Ghat = ws + OFF_GHAT;
    float*  Xbar = ws + OFF_XBAR;
    float*  Wp   = ws + OFF_WP;
    float*  WkTf = ws + OFF_WKTF;
    float*  WvTf = ws + OFF_WVTF;
    float*  cvec = ws + OFF_CVEC;
    float*  Acc  = ws + OFF_ACC;
    ushort* Gbf  = (ushort*)(ws + OFF_GBF);
    ushort* WqT  = (ushort*)(ws + OFF_WQT);
    ushort* WkT  = (ushort*)(ws + OFF_WKT);
    ushort* Wvb  = (ushort*)(ws + OFF_WVB);
    ushort* ZT   = (ushort*)(ws + OFF_ZT);
    ushort* FT   = (ushort*)(ws + OFF_FT);
    ushort* Tbf  = (ushort*)(ws + OFF_TBF);

    gram_mfma<<<dim3(16, 8, 3), 256, 0, stream>>>(x, Pg, Sp, Ghat, Acc);
    reduce_mirror<<<385, 256, 0, stream>>>(Pg, Sp, Gbf, Ghat, S, Xbar);
    stats_quad<<<dim3(64, 3), 256, 0, stream>>>(Wq, Wk, Wv, Ghat, Xbar,
                                                bq, gq, betaq, bk, gk, betak,
                                                bv, gv, betav, Wp, cvec,
                                                WqT, WkT, Wvb, WkTf, WvTf);
    zmida<<<40, 256, 0, stream>>>(WkT, WqT, ZT, Wp, WkTf, WvTf, S, cvec, Acc);
    bcF2<<<97, 256, 0, stream>>>(Gbf, ZT, FT, Wp, cvec, Acc);
    tvg<<<64, 256, 0, stream>>>(Wvb, FT, Tbf, WvTf, cvec, Acc);
    out_mfma<<<dim3(64, 8), 256, 0, stream>>>(Tbf, x, Acc, cvec, (float*)d_out);
}